// Round 1
// baseline (538.126 us; speedup 1.0000x reference)
//
#include <hip/hip_runtime.h>

#define N_NODES 50000
#define N_EDGES 800000
#define F_IN   128
#define F_MID  64
#define F_OUT  40

// ---------------- degree / norm ----------------

__global__ __launch_bounds__(256) void deg_kernel(const int* __restrict__ ei, int* __restrict__ deg) {
    int e = blockIdx.x * 256 + threadIdx.x;
    if (e < N_EDGES) atomicAdd(&deg[ei[N_EDGES + e]], 1);   // col = target
}

__global__ __launch_bounds__(256) void dinv_kernel(const int* __restrict__ deg, float* __restrict__ dinv) {
    int i = blockIdx.x * 256 + threadIdx.x;
    if (i < N_NODES) dinv[i] = rsqrtf((float)deg[i] + 1.0f);  // +1 = self loop
}

// ---------------- GEMM1: hw1 = x @ W1  (128 -> 64) ----------------
// 4 rows per block; one wave per row; lane = output column.

__global__ __launch_bounds__(256) void gemm1_kernel(const float* __restrict__ x,
                                                    const float* __restrict__ W1,
                                                    float* __restrict__ hw1) {
    __shared__ float sW[F_IN * F_MID];   // 32 KB
    __shared__ float sX[4][F_IN];        // 2 KB
    for (int i = threadIdx.x; i < F_IN * F_MID; i += 256) sW[i] = W1[i];
    int row0 = blockIdx.x * 4;
    for (int i = threadIdx.x; i < 4 * F_IN; i += 256) sX[i >> 7][i & 127] = x[row0 * F_IN + i];
    __syncthreads();
    int r    = threadIdx.x >> 6;
    int lane = threadIdx.x & 63;
    float acc = 0.f;
#pragma unroll
    for (int k = 0; k < F_IN; ++k) acc = fmaf(sX[r][k], sW[k * F_MID + lane], acc);
    hw1[(row0 + r) * F_MID + lane] = acc;
}

// ---------------- scatter1: agg1[col] += hw1[row] * dinv[row]*dinv[col] ----------------
// one wave per edge, lane = feature (64 feats == 64 lanes)

__global__ __launch_bounds__(256) void scatter1_kernel(const int* __restrict__ ei,
                                                       const float* __restrict__ dinv,
                                                       const float* __restrict__ hw1,
                                                       float* __restrict__ agg1) {
    int e = blockIdx.x * 4 + (threadIdx.x >> 6);
    int lane = threadIdx.x & 63;
    if (e >= N_EDGES) return;
    int r = ei[e];
    int c = ei[N_EDGES + e];
    float w = dinv[r] * dinv[c];
    atomicAdd(&agg1[c * F_MID + lane], hw1[r * F_MID + lane] * w);
}

// ---------------- relu epilogue: h = relu(agg1 + selfloop + b1), in place on agg1 ----------------

__global__ __launch_bounds__(256) void relu_kernel(const float* __restrict__ hw1,
                                                   const float* __restrict__ dinv,
                                                   const float* __restrict__ b1,
                                                   float* __restrict__ h) {
    int idx = blockIdx.x * 256 + threadIdx.x;
    if (idx >= N_NODES * F_MID) return;
    int row = idx >> 6;
    int c   = idx & 63;
    float d = dinv[row];
    float v = h[idx] + hw1[idx] * d * d + b1[c];
    h[idx] = fmaxf(v, 0.f);
}

// ---------------- GEMM2: hw2 = h @ W2 (64 -> 40) ----------------

__global__ __launch_bounds__(256) void gemm2_kernel(const float* __restrict__ h,
                                                    const float* __restrict__ W2,
                                                    float* __restrict__ hw2) {
    __shared__ float sW[F_MID * F_OUT];  // 10 KB
    for (int i = threadIdx.x; i < F_MID * F_OUT; i += 256) sW[i] = W2[i];
    __syncthreads();
    int idx = blockIdx.x * 256 + threadIdx.x;
    if (idx >= N_NODES * F_OUT) return;
    int r = idx / F_OUT;
    int c = idx % F_OUT;
    float acc = 0.f;
#pragma unroll
    for (int k = 0; k < F_MID; ++k) acc = fmaf(h[r * F_MID + k], sW[k * F_OUT + c], acc);
    hw2[idx] = acc;
}

// ---------------- scatter2: agg2[col] += hw2[row] * norm (40 feats) ----------------
// one thread per (edge, feature)

__global__ __launch_bounds__(256) void scatter2_kernel(const int* __restrict__ ei,
                                                       const float* __restrict__ dinv,
                                                       const float* __restrict__ hw2,
                                                       float* __restrict__ agg2) {
    int idx = blockIdx.x * 256 + threadIdx.x;
    if (idx >= N_EDGES * F_OUT) return;
    int e = idx / F_OUT;
    int j = idx % F_OUT;
    int r = ei[e];
    int c = ei[N_EDGES + e];
    float w = dinv[r] * dinv[c];
    atomicAdd(&agg2[c * F_OUT + j], hw2[r * F_OUT + j] * w);
}

// ---------------- softmax epilogue (fused self-loop + bias) ----------------
// one wave per row; lanes 0..39 active

__global__ __launch_bounds__(256) void softmax_kernel(const float* __restrict__ agg2,
                                                      const float* __restrict__ hw2,
                                                      const float* __restrict__ dinv,
                                                      const float* __restrict__ b2,
                                                      float* __restrict__ out) {
    int row  = blockIdx.x * 4 + (threadIdx.x >> 6);
    int lane = threadIdx.x & 63;
    if (row >= N_NODES) return;
    float d = dinv[row];
    float v = -3.402823466e38f;
    if (lane < F_OUT) v = agg2[row * F_OUT + lane] + hw2[row * F_OUT + lane] * d * d + b2[lane];
    float m = v;
#pragma unroll
    for (int off = 32; off > 0; off >>= 1) m = fmaxf(m, __shfl_xor(m, off, 64));
    float p = (lane < F_OUT) ? __expf(v - m) : 0.f;
    float s = p;
#pragma unroll
    for (int off = 32; off > 0; off >>= 1) s += __shfl_xor(s, off, 64);
    if (lane < F_OUT) out[row * F_OUT + lane] = p / s;
}

// ---------------- launch ----------------

extern "C" void kernel_launch(void* const* d_in, const int* in_sizes, int n_in,
                              void* d_out, int out_size, void* d_ws, size_t ws_size,
                              hipStream_t stream) {
    const float* x  = (const float*)d_in[0];
    const int*   ei = (const int*)d_in[1];     // [2, E] int32
    const float* W1 = (const float*)d_in[2];
    const float* b1 = (const float*)d_in[3];
    const float* W2 = (const float*)d_in[4];
    const float* b2 = (const float*)d_in[5];
    float* out = (float*)d_out;

    char* ws = (char*)d_ws;
    size_t off = 0;
    auto alloc = [&](size_t bytes) -> void* {
        void* p = ws + off;
        off += (bytes + 255) & ~(size_t)255;
        return p;
    };
    int*   deg  = (int*)  alloc(N_NODES * sizeof(int));
    float* dinv = (float*)alloc(N_NODES * sizeof(float));
    float* hw1  = (float*)alloc((size_t)N_NODES * F_MID * sizeof(float));
    float* agg1 = (float*)alloc((size_t)N_NODES * F_MID * sizeof(float));  // becomes h after relu
    float* hw2  = (float*)alloc((size_t)N_NODES * F_OUT * sizeof(float));
    float* agg2 = (float*)alloc((size_t)N_NODES * F_OUT * sizeof(float));

    hipMemsetAsync(deg,  0, N_NODES * sizeof(int), stream);
    hipMemsetAsync(agg1, 0, (size_t)N_NODES * F_MID * sizeof(float), stream);
    hipMemsetAsync(agg2, 0, (size_t)N_NODES * F_OUT * sizeof(float), stream);

    deg_kernel     <<<(N_EDGES + 255) / 256, 256, 0, stream>>>(ei, deg);
    dinv_kernel    <<<(N_NODES + 255) / 256, 256, 0, stream>>>(deg, dinv);
    gemm1_kernel   <<<N_NODES / 4, 256, 0, stream>>>(x, W1, hw1);
    scatter1_kernel<<<N_EDGES / 4, 256, 0, stream>>>(ei, dinv, hw1, agg1);
    relu_kernel    <<<(N_NODES * F_MID + 255) / 256, 256, 0, stream>>>(hw1, dinv, b1, agg1);
    gemm2_kernel   <<<(N_NODES * F_OUT + 255) / 256, 256, 0, stream>>>(agg1, W2, hw2);
    scatter2_kernel<<<(N_EDGES * F_OUT + 255) / 256, 256, 0, stream>>>(ei, dinv, hw2, agg2);
    softmax_kernel <<<(N_NODES + 3) / 4, 256, 0, stream>>>(agg2, hw2, dinv, b2, out);
}

// Round 2
// 501.616 us; speedup vs baseline: 1.0728x; 1.0728x over previous
//
#include <hip/hip_runtime.h>

#define N_NODES 50000
#define N_EDGES 800000
#define F_IN   128
#define F_MID  64
#define F_OUT  40
#define SEG    196   // ceil(N_NODES / 256) for the single-block scan

// ---------------- degree / norm ----------------

__global__ __launch_bounds__(256) void deg_kernel(const int* __restrict__ ei, int* __restrict__ deg) {
    int e = blockIdx.x * 256 + threadIdx.x;
    if (e < N_EDGES) atomicAdd(&deg[ei[N_EDGES + e]], 1);   // col = target
}

__global__ __launch_bounds__(256) void dinv_kernel(const int* __restrict__ deg, float* __restrict__ dinv) {
    int i = blockIdx.x * 256 + threadIdx.x;
    if (i < N_NODES) dinv[i] = rsqrtf((float)deg[i] + 1.0f);  // +1 = self loop
}

// ---------------- exclusive prefix scan (single block, shuffle-based) ----------------
// 256 threads, each owns a contiguous segment of SEG nodes. Serial per-segment
// sums + one wave scan + LDS wave-offset combine: ~20 instructions of sync total.

__global__ __launch_bounds__(256) void scan_kernel(const int* __restrict__ deg,
                                                   int* __restrict__ rowptr,
                                                   int* __restrict__ cursor) {
    __shared__ int wsum[4];
    int tid  = threadIdx.x;
    int lane = tid & 63, wv = tid >> 6;
    int begin = tid * SEG;
    int end   = begin + SEG; if (end > N_NODES) end = N_NODES;
    int sum = 0;
    for (int i = begin; i < end; ++i) sum += deg[i];
    int v = sum;                                  // wave inclusive scan
#pragma unroll
    for (int s = 1; s < 64; s <<= 1) {
        int t = __shfl_up(v, s, 64);
        if (lane >= s) v += t;
    }
    if (lane == 63) wsum[wv] = v;
    __syncthreads();
    int woff = 0;
    for (int w = 0; w < wv; ++w) woff += wsum[w];
    int run = woff + v - sum;                     // exclusive prefix of this segment
    for (int i = begin; i < end; ++i) {
        rowptr[i] = run;
        cursor[i] = run;
        run += deg[i];
    }
    if (tid == 255) rowptr[N_NODES] = run;
}

// ---------------- CSR fill: group edges by destination ----------------

__global__ __launch_bounds__(256) void fill_kernel(const int* __restrict__ ei,
                                                   const float* __restrict__ dinv,
                                                   int* __restrict__ cursor,
                                                   int* __restrict__ srcs,
                                                   float* __restrict__ wgts) {
    int e = blockIdx.x * 256 + threadIdx.x;
    if (e >= N_EDGES) return;
    int r = ei[e];
    int c = ei[N_EDGES + e];
    int pos = atomicAdd(&cursor[c], 1);
    srcs[pos] = r;
    wgts[pos] = dinv[r];     // pre-scale by source norm; dest norm applied once per node
}

// ---------------- GEMM1: hw1 = x @ W1  (128 -> 64), 16 rows/block ----------------

__global__ __launch_bounds__(256) void gemm1_kernel(const float* __restrict__ x,
                                                    const float* __restrict__ W1,
                                                    float* __restrict__ hw1) {
    __shared__ float sW[F_IN * F_MID];   // 32 KB
    __shared__ float sX[16][F_IN];       // 8 KB
    for (int i = threadIdx.x; i < F_IN * F_MID; i += 256) sW[i] = W1[i];
    int row0 = blockIdx.x * 16;
    for (int i = threadIdx.x; i < 16 * F_IN; i += 256) sX[i >> 7][i & 127] = x[row0 * F_IN + i];
    __syncthreads();
    int wv = threadIdx.x >> 6, lane = threadIdx.x & 63;
#pragma unroll
    for (int rr = 0; rr < 4; ++rr) {
        int r = wv * 4 + rr;
        float acc = 0.f;
#pragma unroll
        for (int k = 0; k < F_IN; ++k) acc = fmaf(sX[r][k], sW[k * F_MID + lane], acc);
        hw1[(row0 + r) * F_MID + lane] = acc;
    }
}

// ---------------- gather1 + self-loop + bias + ReLU ----------------
// one wave per node, lane = feature

__global__ __launch_bounds__(256) void gather1_kernel(const int* __restrict__ rowptr,
                                                      const int* __restrict__ srcs,
                                                      const float* __restrict__ wgts,
                                                      const float* __restrict__ hw1,
                                                      const float* __restrict__ dinv,
                                                      const float* __restrict__ b1,
                                                      float* __restrict__ h) {
    int n = blockIdx.x * 4 + (threadIdx.x >> 6);
    int lane = threadIdx.x & 63;
    if (n >= N_NODES) return;
    int s = rowptr[n], e = rowptr[n + 1];
    float acc = 0.f;
    for (int i = s; i < e; ++i) {
        int   src = srcs[i];
        float w   = wgts[i];
        acc = fmaf(w, hw1[src * F_MID + lane], acc);
    }
    float d = dinv[n];
    float v = fmaf(acc, d, hw1[n * F_MID + lane] * d * d) + b1[lane];
    h[n * F_MID + lane] = fmaxf(v, 0.f);
}

// ---------------- GEMM2: hw2 = h @ W2 (64 -> 40) ----------------

__global__ __launch_bounds__(256) void gemm2_kernel(const float* __restrict__ h,
                                                    const float* __restrict__ W2,
                                                    float* __restrict__ hw2) {
    __shared__ float sW[F_MID * F_OUT];  // 10 KB
    for (int i = threadIdx.x; i < F_MID * F_OUT; i += 256) sW[i] = W2[i];
    __syncthreads();
    int idx = blockIdx.x * 256 + threadIdx.x;
    if (idx >= N_NODES * F_OUT) return;
    int r = idx / F_OUT;
    int c = idx % F_OUT;
    float acc = 0.f;
#pragma unroll
    for (int k = 0; k < F_MID; ++k) acc = fmaf(h[r * F_MID + k], sW[k * F_OUT + c], acc);
    hw2[idx] = acc;
}

// ---------------- gather2 + self-loop + bias + softmax ----------------
// one wave per node; lanes 0..39 carry features

__global__ __launch_bounds__(256) void gather2_softmax_kernel(const int* __restrict__ rowptr,
                                                              const int* __restrict__ srcs,
                                                              const float* __restrict__ wgts,
                                                              const float* __restrict__ hw2,
                                                              const float* __restrict__ dinv,
                                                              const float* __restrict__ b2,
                                                              float* __restrict__ out) {
    int n = blockIdx.x * 4 + (threadIdx.x >> 6);
    int lane = threadIdx.x & 63;
    if (n >= N_NODES) return;
    int s = rowptr[n], e = rowptr[n + 1];
    float d = dinv[n];
    float v = -3.402823466e38f;
    if (lane < F_OUT) {
        float acc = 0.f;
        for (int i = s; i < e; ++i)
            acc = fmaf(wgts[i], hw2[srcs[i] * F_OUT + lane], acc);
        v = fmaf(acc, d, hw2[n * F_OUT + lane] * d * d) + b2[lane];
    }
    float m = v;
#pragma unroll
    for (int off = 32; off > 0; off >>= 1) m = fmaxf(m, __shfl_xor(m, off, 64));
    float p = (lane < F_OUT) ? __expf(v - m) : 0.f;
    float su = p;
#pragma unroll
    for (int off = 32; off > 0; off >>= 1) su += __shfl_xor(su, off, 64);
    if (lane < F_OUT) out[n * F_OUT + lane] = p / su;
}

// ---------------- launch ----------------

extern "C" void kernel_launch(void* const* d_in, const int* in_sizes, int n_in,
                              void* d_out, int out_size, void* d_ws, size_t ws_size,
                              hipStream_t stream) {
    const float* x  = (const float*)d_in[0];
    const int*   ei = (const int*)d_in[1];
    const float* W1 = (const float*)d_in[2];
    const float* b1 = (const float*)d_in[3];
    const float* W2 = (const float*)d_in[4];
    const float* b2 = (const float*)d_in[5];
    float* out = (float*)d_out;

    char* ws = (char*)d_ws;
    size_t off = 0;
    auto alloc = [&](size_t bytes) -> void* {
        void* p = ws + off;
        off += (bytes + 255) & ~(size_t)255;
        return p;
    };
    int*   deg    = (int*)  alloc(N_NODES * sizeof(int));
    float* dinv   = (float*)alloc(N_NODES * sizeof(float));
    int*   rowptr = (int*)  alloc((N_NODES + 1) * sizeof(int));
    int*   cursor = (int*)  alloc(N_NODES * sizeof(int));
    int*   srcs   = (int*)  alloc((size_t)N_EDGES * sizeof(int));
    float* wgts   = (float*)alloc((size_t)N_EDGES * sizeof(float));
    float* hw1    = (float*)alloc((size_t)N_NODES * F_MID * sizeof(float));
    float* h      = (float*)alloc((size_t)N_NODES * F_MID * sizeof(float));
    float* hw2    = (float*)alloc((size_t)N_NODES * F_OUT * sizeof(float));

    hipMemsetAsync(deg, 0, N_NODES * sizeof(int), stream);

    deg_kernel  <<<(N_EDGES + 255) / 256, 256, 0, stream>>>(ei, deg);
    dinv_kernel <<<(N_NODES + 255) / 256, 256, 0, stream>>>(deg, dinv);
    scan_kernel <<<1, 256, 0, stream>>>(deg, rowptr, cursor);
    fill_kernel <<<(N_EDGES + 255) / 256, 256, 0, stream>>>(ei, dinv, cursor, srcs, wgts);
    gemm1_kernel<<<N_NODES / 16, 256, 0, stream>>>(x, W1, hw1);
    gather1_kernel<<<(N_NODES + 3) / 4, 256, 0, stream>>>(rowptr, srcs, wgts, hw1, dinv, b1, h);
    gemm2_kernel<<<(N_NODES * F_OUT + 255) / 256, 256, 0, stream>>>(h, W2, hw2);
    gather2_softmax_kernel<<<(N_NODES + 3) / 4, 256, 0, stream>>>(rowptr, srcs, wgts, hw2, dinv, b2, out);
}

// Round 3
// 300.693 us; speedup vs baseline: 1.7896x; 1.6682x over previous
//
#include <hip/hip_runtime.h>

#define N_NODES 50000
#define N_EDGES 800000
#define F_IN   128
#define F_MID  64
#define F_OUT  40
#define SCAN_B 196   // ceil(N_NODES/256) blocks for the hierarchical scan

// ---------------- degree / norm ----------------

__global__ __launch_bounds__(256) void deg_kernel(const int* __restrict__ ei, int* __restrict__ deg) {
    int e = blockIdx.x * 256 + threadIdx.x;
    if (e < N_EDGES) atomicAdd(&deg[ei[N_EDGES + e]], 1);   // col = target
}

__global__ __launch_bounds__(256) void dinv_kernel(const int* __restrict__ deg, float* __restrict__ dinv) {
    int i = blockIdx.x * 256 + threadIdx.x;
    if (i < N_NODES) dinv[i] = rsqrtf((float)deg[i] + 1.0f);  // +1 = self loop
}

// ---------------- hierarchical exclusive scan of deg -> rowptr/cursor ----------------

__global__ __launch_bounds__(256) void bsum_kernel(const int* __restrict__ deg, int* __restrict__ bsum) {
    int idx = blockIdx.x * 256 + threadIdx.x;
    int v = (idx < N_NODES) ? deg[idx] : 0;
#pragma unroll
    for (int off = 32; off > 0; off >>= 1) v += __shfl_xor(v, off, 64);
    __shared__ int ws[4];
    if ((threadIdx.x & 63) == 0) ws[threadIdx.x >> 6] = v;
    __syncthreads();
    if (threadIdx.x == 0) bsum[blockIdx.x] = ws[0] + ws[1] + ws[2] + ws[3];
}

__global__ __launch_bounds__(256) void bscan_kernel(const int* __restrict__ bsum, int* __restrict__ boff) {
    int tid = threadIdx.x;
    int lane = tid & 63, wv = tid >> 6;
    int v = (tid < SCAN_B) ? bsum[tid] : 0;
    int inc = v;
#pragma unroll
    for (int s = 1; s < 64; s <<= 1) {
        int t = __shfl_up(inc, s, 64);
        if (lane >= s) inc += t;
    }
    __shared__ int ws[4];
    if (lane == 63) ws[wv] = inc;
    __syncthreads();
    int woff = 0;
    for (int w = 0; w < wv; ++w) woff += ws[w];
    if (tid < SCAN_B) boff[tid] = woff + inc - v;   // exclusive prefix of block sums
}

__global__ __launch_bounds__(256) void bscan2_kernel(const int* __restrict__ deg,
                                                     const int* __restrict__ boff,
                                                     int* __restrict__ rowptr,
                                                     int* __restrict__ cursor) {
    int idx = blockIdx.x * 256 + threadIdx.x;
    int lane = threadIdx.x & 63, wv = threadIdx.x >> 6;
    int v = (idx < N_NODES) ? deg[idx] : 0;
    int inc = v;
#pragma unroll
    for (int s = 1; s < 64; s <<= 1) {
        int t = __shfl_up(inc, s, 64);
        if (lane >= s) inc += t;
    }
    __shared__ int ws[4];
    if (lane == 63) ws[wv] = inc;
    __syncthreads();
    int off = boff[blockIdx.x];
    for (int w = 0; w < wv; ++w) off += ws[w];
    int ex = off + inc - v;
    if (idx < N_NODES) { rowptr[idx] = ex; cursor[idx] = ex; }
    if (idx == N_NODES - 1) rowptr[N_NODES] = ex + v;   // == N_EDGES
}

// ---------------- CSR fill: group edges by destination ----------------

__global__ __launch_bounds__(256) void fill_kernel(const int* __restrict__ ei,
                                                   const float* __restrict__ dinv,
                                                   int* __restrict__ cursor,
                                                   int* __restrict__ srcs,
                                                   float* __restrict__ wgts) {
    int e = blockIdx.x * 256 + threadIdx.x;
    if (e >= N_EDGES) return;
    int r = ei[e];
    int c = ei[N_EDGES + e];
    int pos = atomicAdd(&cursor[c], 1);
    srcs[pos] = r;
    wgts[pos] = dinv[r];     // pre-scale by source norm; dest norm applied once per node
}

// ---------------- GEMM1: hw1 = x @ W1  (128 -> 64), 8 rows/wave, 32 rows/block ----------------
// x-row reads are wave-uniform -> scalar loads; sW read once per k serves all 8 rows.

__global__ __launch_bounds__(256) void gemm1_kernel(const float* __restrict__ x,
                                                    const float* __restrict__ W1,
                                                    float* __restrict__ hw1) {
    __shared__ float sW[F_IN * F_MID];   // 32 KB
    for (int i = threadIdx.x; i < F_IN * F_MID; i += 256) sW[i] = W1[i];
    __syncthreads();
    int wv   = __builtin_amdgcn_readfirstlane(threadIdx.x >> 6);
    int lane = threadIdx.x & 63;
    int row0 = blockIdx.x * 32 + wv * 8;
    if (row0 >= N_NODES) return;
    float acc[8] = {0.f, 0.f, 0.f, 0.f, 0.f, 0.f, 0.f, 0.f};
    const float* xp = x + (size_t)row0 * F_IN;
    if (row0 + 8 <= N_NODES) {
#pragma unroll 4
        for (int k = 0; k < F_IN; ++k) {
            float w = sW[k * F_MID + lane];
#pragma unroll
            for (int r = 0; r < 8; ++r) acc[r] = fmaf(xp[r * F_IN + k], w, acc[r]);
        }
#pragma unroll
        for (int r = 0; r < 8; ++r) hw1[(size_t)(row0 + r) * F_MID + lane] = acc[r];
    } else {
        int nr = N_NODES - row0;
        for (int k = 0; k < F_IN; ++k) {
            float w = sW[k * F_MID + lane];
            for (int r = 0; r < nr; ++r) acc[r] = fmaf(xp[r * F_IN + k], w, acc[r]);
        }
        for (int r = 0; r < nr; ++r) hw1[(size_t)(row0 + r) * F_MID + lane] = acc[r];
    }
}

// ---------------- gather1 + self-loop + bias + ReLU ----------------
// one wave per node, lane = feature; wave-cooperative edge loads + 4x unrolled row gather

__global__ __launch_bounds__(256) void gather1_kernel(const int* __restrict__ rowptr,
                                                      const int* __restrict__ srcs,
                                                      const float* __restrict__ wgts,
                                                      const float* __restrict__ hw1,
                                                      const float* __restrict__ dinv,
                                                      const float* __restrict__ b1,
                                                      float* __restrict__ h) {
    int n = blockIdx.x * 4 + (threadIdx.x >> 6);
    int lane = threadIdx.x & 63;
    if (n >= N_NODES) return;
    int s = rowptr[n], e = rowptr[n + 1];
    float acc = 0.f;
    for (int base = s; base < e; base += 64) {
        int cnt = e - base; if (cnt > 64) cnt = 64;
        int   ms = (lane < cnt) ? srcs[base + lane] : 0;
        float mw = (lane < cnt) ? wgts[base + lane] : 0.f;
        int j = 0;
        for (; j + 4 <= cnt; j += 4) {
            int i0 = __shfl(ms, j, 64),     i1 = __shfl(ms, j + 1, 64);
            int i2 = __shfl(ms, j + 2, 64), i3 = __shfl(ms, j + 3, 64);
            float w0 = __shfl(mw, j, 64),     w1 = __shfl(mw, j + 1, 64);
            float w2 = __shfl(mw, j + 2, 64), w3 = __shfl(mw, j + 3, 64);
            float v0 = hw1[(size_t)i0 * F_MID + lane];
            float v1 = hw1[(size_t)i1 * F_MID + lane];
            float v2 = hw1[(size_t)i2 * F_MID + lane];
            float v3 = hw1[(size_t)i3 * F_MID + lane];
            acc = fmaf(w0, v0, acc); acc = fmaf(w1, v1, acc);
            acc = fmaf(w2, v2, acc); acc = fmaf(w3, v3, acc);
        }
        for (; j < cnt; ++j) {
            int i0 = __shfl(ms, j, 64);
            float w0 = __shfl(mw, j, 64);
            acc = fmaf(w0, hw1[(size_t)i0 * F_MID + lane], acc);
        }
    }
    float d = dinv[n];
    float v = fmaf(acc, d, hw1[(size_t)n * F_MID + lane] * d * d) + b1[lane];
    h[(size_t)n * F_MID + lane] = fmaxf(v, 0.f);
}

// ---------------- GEMM2: hw2 = h @ W2 (64 -> 40) ----------------

__global__ __launch_bounds__(256) void gemm2_kernel(const float* __restrict__ h,
                                                    const float* __restrict__ W2,
                                                    float* __restrict__ hw2) {
    __shared__ float sW[F_MID * F_OUT];  // 10 KB
    for (int i = threadIdx.x; i < F_MID * F_OUT; i += 256) sW[i] = W2[i];
    __syncthreads();
    int idx = blockIdx.x * 256 + threadIdx.x;
    if (idx >= N_NODES * F_OUT) return;
    int r = idx / F_OUT;
    int c = idx % F_OUT;
    float acc = 0.f;
#pragma unroll
    for (int k = 0; k < F_MID; ++k) acc = fmaf(h[(size_t)r * F_MID + k], sW[k * F_OUT + c], acc);
    hw2[idx] = acc;
}

// ---------------- gather2 + self-loop + bias + softmax ----------------

__global__ __launch_bounds__(256) void gather2_softmax_kernel(const int* __restrict__ rowptr,
                                                              const int* __restrict__ srcs,
                                                              const float* __restrict__ wgts,
                                                              const float* __restrict__ hw2,
                                                              const float* __restrict__ dinv,
                                                              const float* __restrict__ b2,
                                                              float* __restrict__ out) {
    int n = blockIdx.x * 4 + (threadIdx.x >> 6);
    int lane = threadIdx.x & 63;
    if (n >= N_NODES) return;
    int s = rowptr[n], e = rowptr[n + 1];
    float acc = 0.f;
    for (int base = s; base < e; base += 64) {
        int cnt = e - base; if (cnt > 64) cnt = 64;
        int   ms = (lane < cnt) ? srcs[base + lane] : 0;
        float mw = (lane < cnt) ? wgts[base + lane] : 0.f;
        int j = 0;
        for (; j + 4 <= cnt; j += 4) {
            int i0 = __shfl(ms, j, 64),     i1 = __shfl(ms, j + 1, 64);
            int i2 = __shfl(ms, j + 2, 64), i3 = __shfl(ms, j + 3, 64);
            float w0 = __shfl(mw, j, 64),     w1 = __shfl(mw, j + 1, 64);
            float w2 = __shfl(mw, j + 2, 64), w3 = __shfl(mw, j + 3, 64);
            if (lane < F_OUT) {
                float v0 = hw2[(size_t)i0 * F_OUT + lane];
                float v1 = hw2[(size_t)i1 * F_OUT + lane];
                float v2 = hw2[(size_t)i2 * F_OUT + lane];
                float v3 = hw2[(size_t)i3 * F_OUT + lane];
                acc = fmaf(w0, v0, acc); acc = fmaf(w1, v1, acc);
                acc = fmaf(w2, v2, acc); acc = fmaf(w3, v3, acc);
            }
        }
        for (; j < cnt; ++j) {
            int i0 = __shfl(ms, j, 64);
            float w0 = __shfl(mw, j, 64);
            if (lane < F_OUT) acc = fmaf(w0, hw2[(size_t)i0 * F_OUT + lane], acc);
        }
    }
    float d = dinv[n];
    float v = -3.402823466e38f;
    if (lane < F_OUT)
        v = fmaf(acc, d, hw2[(size_t)n * F_OUT + lane] * d * d) + b2[lane];
    float m = v;
#pragma unroll
    for (int off = 32; off > 0; off >>= 1) m = fmaxf(m, __shfl_xor(m, off, 64));
    float p = (lane < F_OUT) ? __expf(v - m) : 0.f;
    float su = p;
#pragma unroll
    for (int off = 32; off > 0; off >>= 1) su += __shfl_xor(su, off, 64);
    if (lane < F_OUT) out[(size_t)n * F_OUT + lane] = p / su;
}

// ---------------- launch ----------------

extern "C" void kernel_launch(void* const* d_in, const int* in_sizes, int n_in,
                              void* d_out, int out_size, void* d_ws, size_t ws_size,
                              hipStream_t stream) {
    const float* x  = (const float*)d_in[0];
    const int*   ei = (const int*)d_in[1];
    const float* W1 = (const float*)d_in[2];
    const float* b1 = (const float*)d_in[3];
    const float* W2 = (const float*)d_in[4];
    const float* b2 = (const float*)d_in[5];
    float* out = (float*)d_out;

    char* ws = (char*)d_ws;
    size_t off = 0;
    auto alloc = [&](size_t bytes) -> void* {
        void* p = ws + off;
        off += (bytes + 255) & ~(size_t)255;
        return p;
    };
    int*   deg    = (int*)  alloc(N_NODES * sizeof(int));
    float* dinv   = (float*)alloc(N_NODES * sizeof(float));
    int*   rowptr = (int*)  alloc((N_NODES + 1) * sizeof(int));
    int*   cursor = (int*)  alloc(N_NODES * sizeof(int));
    int*   bsum   = (int*)  alloc(SCAN_B * sizeof(int));
    int*   boff   = (int*)  alloc(SCAN_B * sizeof(int));
    int*   srcs   = (int*)  alloc((size_t)N_EDGES * sizeof(int));
    float* wgts   = (float*)alloc((size_t)N_EDGES * sizeof(float));
    float* hw1    = (float*)alloc((size_t)N_NODES * F_MID * sizeof(float));
    float* h      = (float*)alloc((size_t)N_NODES * F_MID * sizeof(float));
    float* hw2    = (float*)alloc((size_t)N_NODES * F_OUT * sizeof(float));

    hipMemsetAsync(deg, 0, N_NODES * sizeof(int), stream);

    deg_kernel  <<<(N_EDGES + 255) / 256, 256, 0, stream>>>(ei, deg);
    dinv_kernel <<<(N_NODES + 255) / 256, 256, 0, stream>>>(deg, dinv);
    bsum_kernel <<<SCAN_B, 256, 0, stream>>>(deg, bsum);
    bscan_kernel<<<1, 256, 0, stream>>>(bsum, boff);
    bscan2_kernel<<<SCAN_B, 256, 0, stream>>>(deg, boff, rowptr, cursor);
    fill_kernel <<<(N_EDGES + 255) / 256, 256, 0, stream>>>(ei, dinv, cursor, srcs, wgts);
    gemm1_kernel<<<(N_NODES + 31) / 32, 256, 0, stream>>>(x, W1, hw1);
    gather1_kernel<<<(N_NODES + 3) / 4, 256, 0, stream>>>(rowptr, srcs, wgts, hw1, dinv, b1, h);
    gemm2_kernel<<<(N_NODES * F_OUT + 255) / 256, 256, 0, stream>>>(h, W2, hw2);
    gather2_softmax_kernel<<<(N_NODES + 3) / 4, 256, 0, stream>>>(rowptr, srcs, wgts, hw2, dinv, b2, out);
}

// Round 4
// 281.421 us; speedup vs baseline: 1.9122x; 1.0685x over previous
//
#include <hip/hip_runtime.h>

#define N_NODES 50000
#define N_EDGES 800000
#define F_IN   128
#define F_MID  64
#define F_OUT  40
#define SCAN_B 196   // ceil(N_NODES/256) blocks for the hierarchical scan

// ---------------- degree ----------------

__global__ __launch_bounds__(256) void deg_kernel(const int* __restrict__ ei, int* __restrict__ deg) {
    int e = blockIdx.x * 256 + threadIdx.x;
    if (e < N_EDGES) atomicAdd(&deg[ei[N_EDGES + e]], 1);   // col = target
}

// ---------------- hierarchical exclusive scan of deg -> rowptr/cursor (+dinv) ----------------

__global__ __launch_bounds__(256) void bsum_kernel(const int* __restrict__ deg, int* __restrict__ bsum) {
    int idx = blockIdx.x * 256 + threadIdx.x;
    int v = (idx < N_NODES) ? deg[idx] : 0;
#pragma unroll
    for (int off = 32; off > 0; off >>= 1) v += __shfl_xor(v, off, 64);
    __shared__ int ws[4];
    if ((threadIdx.x & 63) == 0) ws[threadIdx.x >> 6] = v;
    __syncthreads();
    if (threadIdx.x == 0) bsum[blockIdx.x] = ws[0] + ws[1] + ws[2] + ws[3];
}

__global__ __launch_bounds__(256) void bscan_kernel(const int* __restrict__ bsum, int* __restrict__ boff) {
    int tid = threadIdx.x;
    int lane = tid & 63, wv = tid >> 6;
    int v = (tid < SCAN_B) ? bsum[tid] : 0;
    int inc = v;
#pragma unroll
    for (int s = 1; s < 64; s <<= 1) {
        int t = __shfl_up(inc, s, 64);
        if (lane >= s) inc += t;
    }
    __shared__ int ws[4];
    if (lane == 63) ws[wv] = inc;
    __syncthreads();
    int woff = 0;
    for (int w = 0; w < wv; ++w) woff += ws[w];
    if (tid < SCAN_B) boff[tid] = woff + inc - v;   // exclusive prefix of block sums
}

__global__ __launch_bounds__(256) void bscan2_kernel(const int* __restrict__ deg,
                                                     const int* __restrict__ boff,
                                                     int* __restrict__ rowptr,
                                                     int* __restrict__ cursor,
                                                     float* __restrict__ dinv) {
    int idx = blockIdx.x * 256 + threadIdx.x;
    int lane = threadIdx.x & 63, wv = threadIdx.x >> 6;
    int v = (idx < N_NODES) ? deg[idx] : 0;
    int inc = v;
#pragma unroll
    for (int s = 1; s < 64; s <<= 1) {
        int t = __shfl_up(inc, s, 64);
        if (lane >= s) inc += t;
    }
    __shared__ int ws[4];
    if (lane == 63) ws[wv] = inc;
    __syncthreads();
    int off = boff[blockIdx.x];
    for (int w = 0; w < wv; ++w) off += ws[w];
    int ex = off + inc - v;
    if (idx < N_NODES) {
        rowptr[idx] = ex;
        cursor[idx] = ex;
        dinv[idx]   = rsqrtf((float)v + 1.0f);   // +1 = self loop
    }
    if (idx == N_NODES - 1) rowptr[N_NODES] = ex + v;   // == N_EDGES
}

// ---------------- CSR fill: group edges by destination ----------------

__global__ __launch_bounds__(256) void fill_kernel(const int* __restrict__ ei,
                                                   const float* __restrict__ dinv,
                                                   int* __restrict__ cursor,
                                                   int* __restrict__ srcs,
                                                   float* __restrict__ wgts) {
    int e = blockIdx.x * 256 + threadIdx.x;
    if (e >= N_EDGES) return;
    int r = ei[e];
    int c = ei[N_EDGES + e];
    int pos = atomicAdd(&cursor[c], 1);
    srcs[pos] = r;
    wgts[pos] = dinv[r];     // pre-scale by source norm; dest norm applied once per node
}

// ---------------- GEMM1: hw1 = x @ W1  (128 -> 64) ----------------
// 64 rows x 64 cols per block; 256 threads; 4x4 register tile per thread.
// W fully staged (32 KB); X staged in two 64-wide K halves (sX[64][68], +4 pad
// -> 2-way LDS aliasing only, free per m136). Inner step: 1 ds_read_b128 +
// 4 ds_read_b32 + 16 FMA => FMA-limited, ~50 KB LDS -> 3 blocks/CU.

__global__ __launch_bounds__(256) void gemm1_kernel(const float* __restrict__ x,
                                                    const float* __restrict__ W1,
                                                    float* __restrict__ hw1) {
    __shared__ float sW[F_IN * F_MID];   // 32 KB, row-major [k][c]
    __shared__ float sX[64][68];         // 17 KB, one K-half, padded
    int tid = threadIdx.x;
    const float4* W4 = (const float4*)W1;
    float4* sW4 = (float4*)sW;
    for (int i = tid; i < F_IN * F_MID / 4; i += 256) sW4[i] = W4[i];

    int row0 = blockIdx.x * 64;
    int tx = tid & 15, ty = tid >> 4;
    int c0 = tx * 4, r0 = ty * 4;
    float acc[4][4] = {};

    for (int p = 0; p < 2; ++p) {
        __syncthreads();
        // stage 64 rows x 64 cols of this K-half: 4096 floats / 256 thr = 4 float4 each
#pragma unroll
        for (int it = 0; it < 4; ++it) {
            int i = (tid + it * 256) * 4;      // element index in 64x64 tile
            int r = i >> 6, k = i & 63;
            float4 v = make_float4(0.f, 0.f, 0.f, 0.f);
            if (row0 + r < N_NODES)
                v = *(const float4*)&x[(size_t)(row0 + r) * F_IN + p * 64 + k];
            *(float4*)&sX[r][k] = v;
        }
        __syncthreads();
        const float* sWp = sW + p * 64 * F_MID;
#pragma unroll 4
        for (int k = 0; k < 64; ++k) {
            float4 w = *(const float4*)&sWp[k * F_MID + c0];
            float a0 = sX[r0 + 0][k];
            float a1 = sX[r0 + 1][k];
            float a2 = sX[r0 + 2][k];
            float a3 = sX[r0 + 3][k];
            acc[0][0] = fmaf(a0, w.x, acc[0][0]); acc[0][1] = fmaf(a0, w.y, acc[0][1]);
            acc[0][2] = fmaf(a0, w.z, acc[0][2]); acc[0][3] = fmaf(a0, w.w, acc[0][3]);
            acc[1][0] = fmaf(a1, w.x, acc[1][0]); acc[1][1] = fmaf(a1, w.y, acc[1][1]);
            acc[1][2] = fmaf(a1, w.z, acc[1][2]); acc[1][3] = fmaf(a1, w.w, acc[1][3]);
            acc[2][0] = fmaf(a2, w.x, acc[2][0]); acc[2][1] = fmaf(a2, w.y, acc[2][1]);
            acc[2][2] = fmaf(a2, w.z, acc[2][2]); acc[2][3] = fmaf(a2, w.w, acc[2][3]);
            acc[3][0] = fmaf(a3, w.x, acc[3][0]); acc[3][1] = fmaf(a3, w.y, acc[3][1]);
            acc[3][2] = fmaf(a3, w.z, acc[3][2]); acc[3][3] = fmaf(a3, w.w, acc[3][3]);
        }
    }
#pragma unroll
    for (int j = 0; j < 4; ++j) {
        int row = row0 + r0 + j;
        if (row < N_NODES) {
            float4 o = make_float4(acc[j][0], acc[j][1], acc[j][2], acc[j][3]);
            *(float4*)&hw1[(size_t)row * F_MID + c0] = o;
        }
    }
}

// ---------------- gather1 + self-loop + bias + ReLU ----------------
// one wave per node, lane = feature; wave-cooperative edge loads + 4x unrolled row gather

__global__ __launch_bounds__(256) void gather1_kernel(const int* __restrict__ rowptr,
                                                      const int* __restrict__ srcs,
                                                      const float* __restrict__ wgts,
                                                      const float* __restrict__ hw1,
                                                      const float* __restrict__ dinv,
                                                      const float* __restrict__ b1,
                                                      float* __restrict__ h) {
    int n = blockIdx.x * 4 + (threadIdx.x >> 6);
    int lane = threadIdx.x & 63;
    if (n >= N_NODES) return;
    int s = rowptr[n], e = rowptr[n + 1];
    float acc = 0.f;
    for (int base = s; base < e; base += 64) {
        int cnt = e - base; if (cnt > 64) cnt = 64;
        int   ms = (lane < cnt) ? srcs[base + lane] : 0;
        float mw = (lane < cnt) ? wgts[base + lane] : 0.f;
        int j = 0;
        for (; j + 4 <= cnt; j += 4) {
            int i0 = __shfl(ms, j, 64),     i1 = __shfl(ms, j + 1, 64);
            int i2 = __shfl(ms, j + 2, 64), i3 = __shfl(ms, j + 3, 64);
            float w0 = __shfl(mw, j, 64),     w1 = __shfl(mw, j + 1, 64);
            float w2 = __shfl(mw, j + 2, 64), w3 = __shfl(mw, j + 3, 64);
            float v0 = hw1[(size_t)i0 * F_MID + lane];
            float v1 = hw1[(size_t)i1 * F_MID + lane];
            float v2 = hw1[(size_t)i2 * F_MID + lane];
            float v3 = hw1[(size_t)i3 * F_MID + lane];
            acc = fmaf(w0, v0, acc); acc = fmaf(w1, v1, acc);
            acc = fmaf(w2, v2, acc); acc = fmaf(w3, v3, acc);
        }
        for (; j < cnt; ++j) {
            int i0 = __shfl(ms, j, 64);
            float w0 = __shfl(mw, j, 64);
            acc = fmaf(w0, hw1[(size_t)i0 * F_MID + lane], acc);
        }
    }
    float d = dinv[n];
    float v = fmaf(acc, d, hw1[(size_t)n * F_MID + lane] * d * d) + b1[lane];
    h[(size_t)n * F_MID + lane] = fmaxf(v, 0.f);
}

// ---------------- GEMM2: hw2 = h @ W2 (64 -> 40) ----------------

__global__ __launch_bounds__(256) void gemm2_kernel(const float* __restrict__ h,
                                                    const float* __restrict__ W2,
                                                    float* __restrict__ hw2) {
    __shared__ float sW[F_MID * F_OUT];  // 10 KB
    for (int i = threadIdx.x; i < F_MID * F_OUT; i += 256) sW[i] = W2[i];
    __syncthreads();
    int idx = blockIdx.x * 256 + threadIdx.x;
    if (idx >= N_NODES * F_OUT) return;
    int r = idx / F_OUT;
    int c = idx % F_OUT;
    float acc = 0.f;
#pragma unroll
    for (int k = 0; k < F_MID; ++k) acc = fmaf(h[(size_t)r * F_MID + k], sW[k * F_OUT + c], acc);
    hw2[idx] = acc;
}

// ---------------- gather2 + self-loop + bias + softmax ----------------

__global__ __launch_bounds__(256) void gather2_softmax_kernel(const int* __restrict__ rowptr,
                                                              const int* __restrict__ srcs,
                                                              const float* __restrict__ wgts,
                                                              const float* __restrict__ hw2,
                                                              const float* __restrict__ dinv,
                                                              const float* __restrict__ b2,
                                                              float* __restrict__ out) {
    int n = blockIdx.x * 4 + (threadIdx.x >> 6);
    int lane = threadIdx.x & 63;
    if (n >= N_NODES) return;
    int s = rowptr[n], e = rowptr[n + 1];
    float acc = 0.f;
    for (int base = s; base < e; base += 64) {
        int cnt = e - base; if (cnt > 64) cnt = 64;
        int   ms = (lane < cnt) ? srcs[base + lane] : 0;
        float mw = (lane < cnt) ? wgts[base + lane] : 0.f;
        int j = 0;
        for (; j + 4 <= cnt; j += 4) {
            int i0 = __shfl(ms, j, 64),     i1 = __shfl(ms, j + 1, 64);
            int i2 = __shfl(ms, j + 2, 64), i3 = __shfl(ms, j + 3, 64);
            float w0 = __shfl(mw, j, 64),     w1 = __shfl(mw, j + 1, 64);
            float w2 = __shfl(mw, j + 2, 64), w3 = __shfl(mw, j + 3, 64);
            if (lane < F_OUT) {
                float v0 = hw2[(size_t)i0 * F_OUT + lane];
                float v1 = hw2[(size_t)i1 * F_OUT + lane];
                float v2 = hw2[(size_t)i2 * F_OUT + lane];
                float v3 = hw2[(size_t)i3 * F_OUT + lane];
                acc = fmaf(w0, v0, acc); acc = fmaf(w1, v1, acc);
                acc = fmaf(w2, v2, acc); acc = fmaf(w3, v3, acc);
            }
        }
        for (; j < cnt; ++j) {
            int i0 = __shfl(ms, j, 64);
            float w0 = __shfl(mw, j, 64);
            if (lane < F_OUT) acc = fmaf(w0, hw2[(size_t)i0 * F_OUT + lane], acc);
        }
    }
    float d = dinv[n];
    float v = -3.402823466e38f;
    if (lane < F_OUT)
        v = fmaf(acc, d, hw2[(size_t)n * F_OUT + lane] * d * d) + b2[lane];
    float m = v;
#pragma unroll
    for (int off = 32; off > 0; off >>= 1) m = fmaxf(m, __shfl_xor(m, off, 64));
    float p = (lane < F_OUT) ? __expf(v - m) : 0.f;
    float su = p;
#pragma unroll
    for (int off = 32; off > 0; off >>= 1) su += __shfl_xor(su, off, 64);
    if (lane < F_OUT) out[(size_t)n * F_OUT + lane] = p / su;
}

// ---------------- launch ----------------

extern "C" void kernel_launch(void* const* d_in, const int* in_sizes, int n_in,
                              void* d_out, int out_size, void* d_ws, size_t ws_size,
                              hipStream_t stream) {
    const float* x  = (const float*)d_in[0];
    const int*   ei = (const int*)d_in[1];
    const float* W1 = (const float*)d_in[2];
    const float* b1 = (const float*)d_in[3];
    const float* W2 = (const float*)d_in[4];
    const float* b2 = (const float*)d_in[5];
    float* out = (float*)d_out;

    char* ws = (char*)d_ws;
    size_t off = 0;
    auto alloc = [&](size_t bytes) -> void* {
        void* p = ws + off;
        off += (bytes + 255) & ~(size_t)255;
        return p;
    };
    int*   deg    = (int*)  alloc(N_NODES * sizeof(int));
    float* dinv   = (float*)alloc(N_NODES * sizeof(float));
    int*   rowptr = (int*)  alloc((N_NODES + 1) * sizeof(int));
    int*   cursor = (int*)  alloc(N_NODES * sizeof(int));
    int*   bsum   = (int*)  alloc(SCAN_B * sizeof(int));
    int*   boff   = (int*)  alloc(SCAN_B * sizeof(int));
    int*   srcs   = (int*)  alloc((size_t)N_EDGES * sizeof(int));
    float* wgts   = (float*)alloc((size_t)N_EDGES * sizeof(float));
    float* hw1    = (float*)alloc((size_t)N_NODES * F_MID * sizeof(float));
    float* h      = (float*)alloc((size_t)N_NODES * F_MID * sizeof(float));
    float* hw2    = (float*)alloc((size_t)N_NODES * F_OUT * sizeof(float));

    hipMemsetAsync(deg, 0, N_NODES * sizeof(int), stream);

    deg_kernel   <<<(N_EDGES + 255) / 256, 256, 0, stream>>>(ei, deg);
    bsum_kernel  <<<SCAN_B, 256, 0, stream>>>(deg, bsum);
    bscan_kernel <<<1, 256, 0, stream>>>(bsum, boff);
    bscan2_kernel<<<SCAN_B, 256, 0, stream>>>(deg, boff, rowptr, cursor, dinv);
    fill_kernel  <<<(N_EDGES + 255) / 256, 256, 0, stream>>>(ei, dinv, cursor, srcs, wgts);
    gemm1_kernel <<<(N_NODES + 63) / 64, 256, 0, stream>>>(x, W1, hw1);
    gather1_kernel<<<(N_NODES + 3) / 4, 256, 0, stream>>>(rowptr, srcs, wgts, hw1, dinv, b1, h);
    gemm2_kernel <<<(N_NODES * F_OUT + 255) / 256, 256, 0, stream>>>(h, W2, hw2);
    gather2_softmax_kernel<<<(N_NODES + 3) / 4, 256, 0, stream>>>(rowptr, srcs, wgts, hw2, dinv, b2, out);
}